// Round 1
// baseline (1007.496 us; speedup 1.0000x reference)
//
#include <hip/hip_runtime.h>
#include <hip/hip_bf16.h>
#include <hip/hip_fp16.h>
#include <cstdint>

#define N_NODES 100000
#define N_EDGES 3200000
#define F_IN    512
#define F_HID   256
#define F_OUT   64
#define CAP     96   // max ELL slots/row; Poisson(32) max over 100K rows ~65, 96 is safe

#define G_SCATTER 12500   // N_EDGES / 256 exactly
#define G_GEMM1   3125    // N_NODES / 32 exactly
#define LDS_STRIDE 272    // 544B row stride -> <=4-way LDS bank conflict on ds_read_b128

typedef _Float16 half8_t __attribute__((ext_vector_type(8)));
typedef _Float16 half4_t __attribute__((ext_vector_type(4)));
typedef float    float4_t __attribute__((ext_vector_type(4)));

// ---------------- prep: zero cursors + W0/W1 -> fp16 transposed ----------------
// Must run BEFORE the mega kernel (gemm1 blocks read W0T; no intra-dispatch ordering).

__global__ __launch_bounds__(256) void prep_kernel(
    const float* __restrict__ W0, const float* __restrict__ W1,
    _Float16* __restrict__ W0T, _Float16* __restrict__ W1T,
    int* __restrict__ cursor) {
    int i = blockIdx.x * 256 + threadIdx.x;
    if (i < N_NODES) cursor[i] = 0;
    if (i < F_HID * F_IN) {                 // W0T[n][k] = W0[k][n], 256x512
        int n = i >> 9, k = i & 511;
        W0T[i] = (_Float16)W0[k * F_HID + n];
    }
    int j = i - F_HID * F_IN;
    if (j >= 0 && j < F_OUT * F_HID) {      // W1T[n][k] = W1[k][n], 64x256
        int n = j >> 8, k = j & 255;
        W1T[j] = (_Float16)W1[k * F_OUT + n];
    }
}

// ---------------- mega: ELL scatter (packed int2)  ||  GEMM1 (X @ W0 -> fp16 H0) ----
// Independent work grid-fused into one dispatch: scatter is scattered-write/atomic
// latency-bound (VALUBusy 0.5%), gemm1 is compute-bound -> co-residency hides gemm1.
// __launch_bounds__(256,6): cap VGPR ~85 so the scatter branch keeps 24 waves/CU
// (its measured 75% occupancy). gemm1 uses acc[2][4] (32 rows x 256 cols/block) to fit.
// Layouts (guide-verified): A[m=lane&15][k=quad*8+j]; B[k][n=lane&15];
// D: col(n)=lane&15, row(m)=quad*4+reg.

__global__ __launch_bounds__(256, 6) void mega_kernel(
    const int* __restrict__ erows, const int* __restrict__ ecols,
    const float* __restrict__ evals, int* __restrict__ cursor,
    int2* __restrict__ ell,
    const float* __restrict__ X, const _Float16* __restrict__ W0T,
    _Float16* __restrict__ H0) {

    if (blockIdx.x < G_SCATTER) {
        // one 8B packed store per edge instead of two 4B stores to separate arrays
        int e = blockIdx.x * 256 + threadIdx.x;   // G_SCATTER*256 == N_EDGES exactly
        int r = erows[e];
        int p = atomicAdd(&cursor[r], 1);
        if (p < CAP)
            ell[(size_t)r * CAP + p] = make_int2(ecols[e], __float_as_int(evals[e]));
        return;
    }

    const int blk  = blockIdx.x - G_SCATTER;
    const int wave = threadIdx.x >> 6;
    const int lane = threadIdx.x & 63;
    const int l15  = lane & 15;
    const int quad = lane >> 4;
    const int m0   = blk * 32;        // G_GEMM1*32 == N_NODES exactly, no clamp needed
    const int n0   = wave * 64;

    float4_t acc[2][4] = {};   // [mt][nt]

    for (int k0 = 0; k0 < F_IN; k0 += 32) {
        const int kk = k0 + quad * 8;
        half8_t b[4];
        #pragma unroll
        for (int nt = 0; nt < 4; nt++)
            b[nt] = *(const half8_t*)(W0T + (size_t)(n0 + nt * 16 + l15) * F_IN + kk);

        half8_t a[2];
        #pragma unroll
        for (int mt = 0; mt < 2; mt++) {
            const float* p = X + (size_t)(m0 + mt * 16 + l15) * F_IN + kk;
            float4_t lo = *(const float4_t*)p;
            float4_t hi = *(const float4_t*)(p + 4);
            half8_t f;
            f[0] = (_Float16)lo[0]; f[1] = (_Float16)lo[1];
            f[2] = (_Float16)lo[2]; f[3] = (_Float16)lo[3];
            f[4] = (_Float16)hi[0]; f[5] = (_Float16)hi[1];
            f[6] = (_Float16)hi[2]; f[7] = (_Float16)hi[3];
            a[mt] = f;
        }

        #pragma unroll
        for (int mt = 0; mt < 2; mt++)
            #pragma unroll
            for (int nt = 0; nt < 4; nt++)
                acc[mt][nt] = __builtin_amdgcn_mfma_f32_16x16x32_f16(
                    a[mt], b[nt], acc[mt][nt], 0, 0, 0);
    }

    #pragma unroll
    for (int mt = 0; mt < 2; mt++)
        #pragma unroll
        for (int reg = 0; reg < 4; reg++) {
            int m = m0 + mt * 16 + quad * 4 + reg;
            #pragma unroll
            for (int nt = 0; nt < 4; nt++)
                H0[(size_t)m * F_HID + n0 + nt * 16 + l15] =
                    (_Float16)acc[mt][nt][reg];
        }
}

// ---------------- SpMM layer 1 + ReLU + fused GEMM2 ----------------
// Block = 4 waves handles 16 rows. Phase 1: wave w gathers rows 4w..4w+3 (wave-per-row,
// lane t = feats [4t,4t+4), fp32 accumulate), ReLU, stage fp16 rows in LDS.
// Phase 2: one 16x256 @ 256x64 MFMA tile: wave w computes classes [16w,16w+16).
// Deletes the H1 round-trip (51.2MB write + 51.2MB read) and the gemm2 dispatch.

__global__ __launch_bounds__(256) void spmm_relu_gemm2_kernel(
    const _Float16* __restrict__ H0, const int2* __restrict__ ell,
    const int* __restrict__ cursor, const _Float16* __restrict__ W1T,
    _Float16* __restrict__ H2) {
    __shared__ _Float16 hrow[16][LDS_STRIDE];

    const int wave = threadIdx.x >> 6;
    const int t    = threadIdx.x & 63;
    const int base = blockIdx.x * 16;     // 6250*16 == N_NODES exactly
    const half4_t* H0v = (const half4_t*)H0;   // unit = 4 feats

    for (int rr = 0; rr < 4; rr++) {
        const int local = wave * 4 + rr;
        const int r = base + local;
        int n = cursor[r]; if (n > CAP) n = CAP;
        const int2* cv = ell + (size_t)r * CAP;

        float4_t acc = {};
        int j = 0;
        for (; j + 4 <= n; j += 4) {
            int4 e0 = *(const int4*)(cv + j);       // edges j, j+1
            int4 e1 = *(const int4*)(cv + j + 2);   // edges j+2, j+3
            half4_t g0 = H0v[(size_t)e0.x * 64 + t];
            half4_t g1 = H0v[(size_t)e0.z * 64 + t];
            half4_t g2 = H0v[(size_t)e1.x * 64 + t];
            half4_t g3 = H0v[(size_t)e1.z * 64 + t];
            float v0 = __int_as_float(e0.y), v1 = __int_as_float(e0.w);
            float v2 = __int_as_float(e1.y), v3 = __int_as_float(e1.w);
            #pragma unroll
            for (int i = 0; i < 4; i++) {
                acc[i] = fmaf(v0, (float)g0[i], acc[i]);
                acc[i] = fmaf(v1, (float)g1[i], acc[i]);
                acc[i] = fmaf(v2, (float)g2[i], acc[i]);
                acc[i] = fmaf(v3, (float)g3[i], acc[i]);
            }
        }
        for (; j < n; j++) {
            int2 e = cv[j];
            half4_t g = H0v[(size_t)e.x * 64 + t];
            float vv = __int_as_float(e.y);
            #pragma unroll
            for (int i = 0; i < 4; i++) acc[i] = fmaf(vv, (float)g[i], acc[i]);
        }
        half4_t o;
        #pragma unroll
        for (int i = 0; i < 4; i++) o[i] = (_Float16)fmaxf(acc[i], 0.f);
        *(half4_t*)(&hrow[local][t * 4]) = o;
    }
    __syncthreads();

    // GEMM2 tile: D[16 rows][16 classes] per wave, K=256 in 8 steps
    const int l15  = t & 15;
    const int quad = t >> 4;
    float4_t acc2 = {};
    #pragma unroll
    for (int k0 = 0; k0 < F_HID; k0 += 32) {
        const int kk = k0 + quad * 8;
        half8_t a = *(const half8_t*)(&hrow[l15][kk]);   // A[m=l15][k]
        half8_t b = *(const half8_t*)(W1T + (size_t)(wave * 16 + l15) * F_HID + kk);
        acc2 = __builtin_amdgcn_mfma_f32_16x16x32_f16(a, b, acc2, 0, 0, 0);
    }
    #pragma unroll
    for (int reg = 0; reg < 4; reg++) {
        int m = base + quad * 4 + reg;
        H2[(size_t)m * F_OUT + wave * 16 + l15] = (_Float16)acc2[reg];
    }
}

// ---------------- SpMM layer 2 + fused softmax (packed ELL) ----------------

__global__ __launch_bounds__(256) void spmm_softmax_kernel(
    const _Float16* __restrict__ H2, const int2* __restrict__ ell,
    const int* __restrict__ cursor, float* __restrict__ out) {
    const int lane = threadIdx.x & 63;
    const int r = blockIdx.x * 4 + (threadIdx.x >> 6);
    int n = cursor[r]; if (n > CAP) n = CAP;
    const int2* cv = ell + (size_t)r * CAP;

    float acc = 0.f;
    int j = 0;
    for (; j + 4 <= n; j += 4) {
        int4 e0 = *(const int4*)(cv + j);
        int4 e1 = *(const int4*)(cv + j + 2);
        acc = fmaf(__int_as_float(e0.y), (float)H2[(size_t)e0.x * F_OUT + lane], acc);
        acc = fmaf(__int_as_float(e0.w), (float)H2[(size_t)e0.z * F_OUT + lane], acc);
        acc = fmaf(__int_as_float(e1.y), (float)H2[(size_t)e1.x * F_OUT + lane], acc);
        acc = fmaf(__int_as_float(e1.w), (float)H2[(size_t)e1.z * F_OUT + lane], acc);
    }
    for (; j < n; j++) {
        int2 e = cv[j];
        acc = fmaf(__int_as_float(e.y), (float)H2[(size_t)e.x * F_OUT + lane], acc);
    }

    float m = acc;
    #pragma unroll
    for (int o = 32; o >= 1; o >>= 1) m = fmaxf(m, __shfl_xor(m, o, 64));
    float e = expf(acc - m);
    float s = e;
    #pragma unroll
    for (int o = 32; o >= 1; o >>= 1) s += __shfl_xor(s, o, 64);
    out[(size_t)r * F_OUT + lane] = e / s;
}

// ---------------- launcher ----------------

extern "C" void kernel_launch(void* const* d_in, const int* in_sizes, int n_in,
                              void* d_out, int out_size, void* d_ws, size_t ws_size,
                              hipStream_t stream) {
    const float* X     = (const float*)d_in[0];
    const int*   erows = (const int*)  d_in[1];
    const int*   ecols = (const int*)  d_in[2];
    const float* evals = (const float*)d_in[3];
    const float* W0    = (const float*)d_in[4];
    const float* W1    = (const float*)d_in[5];
    float* out = (float*)d_out;

    // workspace layout (all regions 16B-aligned); ~141.5 MB total (was ~192 MB)
    char* p = (char*)d_ws;
    _Float16* H0  = (_Float16*)p; p += (size_t)N_NODES * F_HID * 2;   // 51.2 MB
    _Float16* H2  = (_Float16*)p; p += (size_t)N_NODES * F_OUT * 2;   // 12.8 MB
    _Float16* W0T = (_Float16*)p; p += (size_t)F_HID * F_IN * 2;      // 256 KB
    _Float16* W1T = (_Float16*)p; p += (size_t)F_OUT * F_HID * 2;     // 32 KB
    int*  cursor  = (int*)p;      p += (size_t)N_NODES * 4;           // 0.4 MB
    int2* ell     = (int2*)p;                                         // 76.8 MB packed

    // 1. zero cursors + convert weights (576*256 == 147456 == exactly W0T+W1T elems)
    prep_kernel<<<576, 256, 0, stream>>>(W0, W1, W0T, W1T, cursor);

    // 2. ELL scatter || GEMM1 (independent; compute hides under scatter latency)
    mega_kernel<<<G_SCATTER + G_GEMM1, 256, 0, stream>>>(
        erows, ecols, evals, cursor, ell, X, W0T, H0);

    // 3. H2 = fp16((relu(A @ H0)) @ W1)  -- H1 never touches HBM
    spmm_relu_gemm2_kernel<<<N_NODES / 16, 256, 0, stream>>>(H0, ell, cursor, W1T, H2);

    // 4. out = softmax(A @ H2)
    spmm_softmax_kernel<<<N_NODES / 4, 256, 0, stream>>>(H2, ell, cursor, out);
}

// Round 2
// 934.557 us; speedup vs baseline: 1.0780x; 1.0780x over previous
//
#include <hip/hip_runtime.h>
#include <hip/hip_bf16.h>
#include <hip/hip_fp16.h>
#include <cstdint>

#define N_NODES 100000
#define N_EDGES 3200000
#define F_IN    512
#define F_HID   256
#define F_OUT   64
#define CAP     96    // max ELL slots/row; Poisson(32) max over 100K rows ~65, 96 is safe

#define NSHARD   4          // scatter row-range phases; ELL slice 19.2MB -> L2-resident
#define SHARD_SZ 25000      // N_NODES / NSHARD
#define G_SCATTER 12500     // N_EDGES / 256 exactly
#define NSLICE   4          // H0 feature slabs of 64 feats (12.8MB each -> L2-resident)
#define LDS_STRIDE 272      // 544B row stride, 16B-aligned; 4-way bank conflict (short phase)

typedef _Float16 half8_t __attribute__((ext_vector_type(8)));
typedef _Float16 half4_t __attribute__((ext_vector_type(4)));
typedef float    float4_t __attribute__((ext_vector_type(4)));

// ---------------- prep: zero cursors + W0/W1 -> fp16 transposed ----------------

__global__ __launch_bounds__(256) void prep_kernel(
    const float* __restrict__ W0, const float* __restrict__ W1,
    _Float16* __restrict__ W0T, _Float16* __restrict__ W1T,
    int* __restrict__ cursor) {
    int i = blockIdx.x * 256 + threadIdx.x;
    if (i < N_NODES) cursor[i] = 0;
    if (i < F_HID * F_IN) {                 // W0T[n][k] = W0[k][n], 256x512
        int n = i >> 9, k = i & 511;
        W0T[i] = (_Float16)W0[k * F_HID + n];
    }
    int j = i - F_HID * F_IN;
    if (j >= 0 && j < F_OUT * F_HID) {      // W1T[n][k] = W1[k][n], 64x256
        int n = j >> 8, k = j & 255;
        W1T[j] = (_Float16)W1[k * F_OUT + n];
    }
}

// ---------------- ELL scatter, row-range sharded ----------------
// 4 sequential phases over the edge list; phase k only processes rows in
// [25000k, 25000(k+1)) so the scattered 8B writes land in a 19.2MB ELL slice
// (+100KB cursor slice) that stays L2-resident: lines absorb ~8 slot-writes
// before write-back instead of one partial-line HBM write per edge.
// Cost: erows re-read per phase (4 x 12.8MB streaming) -- cheap.

__global__ __launch_bounds__(256) void ell_scatter_kernel(
    const int* __restrict__ erows, const int* __restrict__ ecols,
    const float* __restrict__ evals, int* __restrict__ cursor,
    int2* __restrict__ ell) {
    const int shard = blockIdx.x / G_SCATTER;            // phases in dispatch order
    const int e = (blockIdx.x % G_SCATTER) * 256 + threadIdx.x;
    int r = erows[e];
    if (r / SHARD_SZ != shard) return;
    int p = atomicAdd(&cursor[r], 1);
    if (p < CAP)
        ell[(size_t)r * CAP + p] = make_int2(ecols[e], __float_as_int(evals[e]));
}

// ---------------- GEMM1: H0 = fp16(X @ W0), sliced output layout ----------------
// Block = 4 waves covers 64 m-rows x all 256 n (X read ONCE from HBM).
// Wave w covers n in [64w, 64w+64) and writes feature-slab w: H0s[w][node][64].
// Layouts (guide-verified): A[m=lane&15][k=quad*8+j]; B[k][n=lane&15];
// D: col(n)=lane&15, row(m)=quad*4+reg.

__global__ __launch_bounds__(256) void gemm1_mfma_kernel(
    const float* __restrict__ X, const _Float16* __restrict__ W0T,
    _Float16* __restrict__ H0) {
    const int wave = threadIdx.x >> 6;
    const int lane = threadIdx.x & 63;
    const int l15  = lane & 15;
    const int quad = lane >> 4;
    const int m0   = blockIdx.x * 64;
    const int n0   = wave * 64;

    float4_t acc[4][4] = {};   // [mt][nt]

    int row[4];
    #pragma unroll
    for (int mt = 0; mt < 4; mt++) {
        int r = m0 + mt * 16 + l15;
        row[mt] = r < N_NODES ? r : N_NODES - 1;  // clamp: garbage rows never stored
    }

    for (int k0 = 0; k0 < F_IN; k0 += 32) {
        const int kk = k0 + quad * 8;
        half8_t b[4];
        #pragma unroll
        for (int nt = 0; nt < 4; nt++)
            b[nt] = *(const half8_t*)(W0T + (size_t)(n0 + nt * 16 + l15) * F_IN + kk);

        half8_t a[4];
        #pragma unroll
        for (int mt = 0; mt < 4; mt++) {
            const float* p = X + (size_t)row[mt] * F_IN + kk;
            float4_t lo = *(const float4_t*)p;
            float4_t hi = *(const float4_t*)(p + 4);
            half8_t f;
            f[0] = (_Float16)lo[0]; f[1] = (_Float16)lo[1];
            f[2] = (_Float16)lo[2]; f[3] = (_Float16)lo[3];
            f[4] = (_Float16)hi[0]; f[5] = (_Float16)hi[1];
            f[6] = (_Float16)hi[2]; f[7] = (_Float16)hi[3];
            a[mt] = f;
        }

        #pragma unroll
        for (int mt = 0; mt < 4; mt++)
            #pragma unroll
            for (int nt = 0; nt < 4; nt++)
                acc[mt][nt] = __builtin_amdgcn_mfma_f32_16x16x32_f16(
                    a[mt], b[nt], acc[mt][nt], 0, 0, 0);
    }

    // store into feature-slab `wave`: H0[(wave*N + m)*64 + (nt*16 + l15)]
    #pragma unroll
    for (int mt = 0; mt < 4; mt++)
        #pragma unroll
        for (int reg = 0; reg < 4; reg++) {
            int m = m0 + mt * 16 + quad * 4 + reg;
            if (m < N_NODES) {
                #pragma unroll
                for (int nt = 0; nt < 4; nt++)
                    H0[((size_t)wave * N_NODES + m) * 64 + nt * 16 + l15] =
                        (_Float16)acc[mt][nt][reg];
            }
        }
}

// ---------------- SpMM layer 1 + ReLU + fused GEMM2, sliced gather ----------------
// Block = 16 rows; one 16-lane group per row (grp = tid>>4), lane-in-group covers
// 4 feats of the current 64-feat slice. Slice loop s=0..3 gathers from slab s
// (12.8MB, L2-resident) -- per wave-instruction: 4 edges x 128B = 512B, same
// efficiency as the unsliced 512B-row gather but with 4x smaller working set.
// Then ReLU -> LDS -> one 16x256 @ 256x64 MFMA tile (wave w: classes [16w,16w+16)).
// H1 never touches HBM.

__global__ __launch_bounds__(256) void spmm_relu_gemm2_kernel(
    const _Float16* __restrict__ H0, const int2* __restrict__ ell,
    const int* __restrict__ cursor, const _Float16* __restrict__ W1T,
    _Float16* __restrict__ H2) {
    __shared__ _Float16 hrow[16][LDS_STRIDE];

    const int t    = threadIdx.x & 63;
    const int grp  = threadIdx.x >> 4;    // 0..15: local row
    const int sub  = threadIdx.x & 15;    // feat-quad within slice
    const int base = blockIdx.x * 16;     // 6250*16 == N_NODES exactly
    const int r    = base + grp;

    int n = cursor[r]; if (n > CAP) n = CAP;
    const int2* cv = ell + (size_t)r * CAP;

    for (int s = 0; s < NSLICE; s++) {
        const half4_t* slab = (const half4_t*)(H0 + (size_t)s * N_NODES * 64);
        float4_t acc = {};
        int j = 0;
        for (; j + 4 <= n; j += 4) {
            int4 e0 = *(const int4*)(cv + j);       // edges j, j+1 (broadcast in group)
            int4 e1 = *(const int4*)(cv + j + 2);   // edges j+2, j+3
            half4_t g0 = slab[(size_t)e0.x * 16 + sub];
            half4_t g1 = slab[(size_t)e0.z * 16 + sub];
            half4_t g2 = slab[(size_t)e1.x * 16 + sub];
            half4_t g3 = slab[(size_t)e1.z * 16 + sub];
            float v0 = __int_as_float(e0.y), v1 = __int_as_float(e0.w);
            float v2 = __int_as_float(e1.y), v3 = __int_as_float(e1.w);
            #pragma unroll
            for (int i = 0; i < 4; i++) {
                acc[i] = fmaf(v0, (float)g0[i], acc[i]);
                acc[i] = fmaf(v1, (float)g1[i], acc[i]);
                acc[i] = fmaf(v2, (float)g2[i], acc[i]);
                acc[i] = fmaf(v3, (float)g3[i], acc[i]);
            }
        }
        for (; j < n; j++) {
            int2 e = cv[j];
            half4_t g = slab[(size_t)e.x * 16 + sub];
            float vv = __int_as_float(e.y);
            #pragma unroll
            for (int i = 0; i < 4; i++) acc[i] = fmaf(vv, (float)g[i], acc[i]);
        }
        half4_t o;
        #pragma unroll
        for (int i = 0; i < 4; i++) o[i] = (_Float16)fmaxf(acc[i], 0.f);
        *(half4_t*)(&hrow[grp][s * 64 + sub * 4]) = o;
    }
    __syncthreads();

    // GEMM2 tile: D[16 rows][16 classes] per wave, K=256 in 8 steps
    const int wave = threadIdx.x >> 6;
    const int l15  = t & 15;
    const int quad = t >> 4;
    float4_t acc2 = {};
    #pragma unroll
    for (int k0 = 0; k0 < F_HID; k0 += 32) {
        const int kk = k0 + quad * 8;
        half8_t a = *(const half8_t*)(&hrow[l15][kk]);   // A[m=l15][k]
        half8_t b = *(const half8_t*)(W1T + (size_t)(wave * 16 + l15) * F_HID + kk);
        acc2 = __builtin_amdgcn_mfma_f32_16x16x32_f16(a, b, acc2, 0, 0, 0);
    }
    #pragma unroll
    for (int reg = 0; reg < 4; reg++) {
        int m = base + quad * 4 + reg;
        H2[(size_t)m * F_OUT + wave * 16 + l15] = (_Float16)acc2[reg];
    }
}

// ---------------- SpMM layer 2 + fused softmax (packed ELL) ----------------

__global__ __launch_bounds__(256) void spmm_softmax_kernel(
    const _Float16* __restrict__ H2, const int2* __restrict__ ell,
    const int* __restrict__ cursor, float* __restrict__ out) {
    const int lane = threadIdx.x & 63;
    const int r = blockIdx.x * 4 + (threadIdx.x >> 6);
    int n = cursor[r]; if (n > CAP) n = CAP;
    const int2* cv = ell + (size_t)r * CAP;

    float acc = 0.f;
    int j = 0;
    for (; j + 4 <= n; j += 4) {
        int4 e0 = *(const int4*)(cv + j);
        int4 e1 = *(const int4*)(cv + j + 2);
        acc = fmaf(__int_as_float(e0.y), (float)H2[(size_t)e0.x * F_OUT + lane], acc);
        acc = fmaf(__int_as_float(e0.w), (float)H2[(size_t)e0.z * F_OUT + lane], acc);
        acc = fmaf(__int_as_float(e1.y), (float)H2[(size_t)e1.x * F_OUT + lane], acc);
        acc = fmaf(__int_as_float(e1.w), (float)H2[(size_t)e1.z * F_OUT + lane], acc);
    }
    for (; j < n; j++) {
        int2 e = cv[j];
        acc = fmaf(__int_as_float(e.y), (float)H2[(size_t)e.x * F_OUT + lane], acc);
    }

    float m = acc;
    #pragma unroll
    for (int o = 32; o >= 1; o >>= 1) m = fmaxf(m, __shfl_xor(m, o, 64));
    float e = expf(acc - m);
    float s = e;
    #pragma unroll
    for (int o = 32; o >= 1; o >>= 1) s += __shfl_xor(s, o, 64);
    out[(size_t)r * F_OUT + lane] = e / s;
}

// ---------------- launcher ----------------

extern "C" void kernel_launch(void* const* d_in, const int* in_sizes, int n_in,
                              void* d_out, int out_size, void* d_ws, size_t ws_size,
                              hipStream_t stream) {
    const float* X     = (const float*)d_in[0];
    const int*   erows = (const int*)  d_in[1];
    const int*   ecols = (const int*)  d_in[2];
    const float* evals = (const float*)d_in[3];
    const float* W0    = (const float*)d_in[4];
    const float* W1    = (const float*)d_in[5];
    float* out = (float*)d_out;

    // workspace layout (all regions 16B-aligned); ~141.5 MB total
    char* p = (char*)d_ws;
    _Float16* H0  = (_Float16*)p; p += (size_t)N_NODES * F_HID * 2;   // 51.2 MB (4 slabs)
    _Float16* H2  = (_Float16*)p; p += (size_t)N_NODES * F_OUT * 2;   // 12.8 MB
    _Float16* W0T = (_Float16*)p; p += (size_t)F_HID * F_IN * 2;      // 256 KB
    _Float16* W1T = (_Float16*)p; p += (size_t)F_OUT * F_HID * 2;     // 32 KB
    int*  cursor  = (int*)p;      p += (size_t)N_NODES * 4;           // 0.4 MB
    int2* ell     = (int2*)p;                                         // 76.8 MB packed

    // 1. zero cursors + convert weights (576*256 == 147456 == exactly W0T+W1T elems)
    prep_kernel<<<576, 256, 0, stream>>>(W0, W1, W0T, W1T, cursor);

    // 2. ELL build, 4 row-range phases (writes L2-resident per phase)
    ell_scatter_kernel<<<NSHARD * G_SCATTER, 256, 0, stream>>>(
        erows, ecols, evals, cursor, ell);

    // 3. H0 = fp16(X @ W0), sliced [4][N][64] layout
    gemm1_mfma_kernel<<<(N_NODES + 63) / 64, 256, 0, stream>>>(X, W0T, H0);

    // 4. H2 = fp16((relu(A @ H0)) @ W1)  -- H1 never touches HBM
    spmm_relu_gemm2_kernel<<<N_NODES / 16, 256, 0, stream>>>(H0, ell, cursor, W1T, H2);

    // 5. out = softmax(A @ H2)
    spmm_softmax_kernel<<<N_NODES / 4, 256, 0, stream>>>(H2, ell, cursor, out);
}